// Round 4
// baseline (513.406 us; speedup 1.0000x reference)
//
#include <hip/hip_runtime.h>
#include <cstdint>
#include <cstddef>

#define BATCH 4096
#define STATE 512
#define NONLIN 1024
#define ACTION 256
#define NMAPS 12   // tanh-map applications; contraction L~0.58 -> trunc err < 0.004

typedef __attribute__((ext_vector_type(8))) short short8;
typedef __attribute__((ext_vector_type(4))) float f32x4;

__device__ __forceinline__ unsigned short f2bf(float f) {
  unsigned u = __float_as_uint(f);
  return (unsigned short)((u + 0x7FFFu + ((u >> 16) & 1u)) >> 16);
}
// tanh(x) = 1 - 2/(exp(2x)+1); exact limits at +-inf, no sign dance
__device__ __forceinline__ float fast_tanh(float x) {
  return 1.0f - 2.0f / (__expf(2.0f * x) + 1.0f);
}

// ============================ prologue kernels =============================
__global__ void convert_kernel(const float* __restrict__ in,
                               unsigned short* __restrict__ out, int n4) {
  int i = blockIdx.x * blockDim.x + threadIdx.x;
  if (i >= n4) return;
  float4 v = reinterpret_cast<const float4*>(in)[i];
  ushort4 o;
  o.x = f2bf(v.x); o.y = f2bf(v.y); o.z = f2bf(v.z); o.w = f2bf(v.w);
  reinterpret_cast<ushort4*>(out)[i] = o;
}

__global__ void transpose_kernel(const float* __restrict__ in,
                                 unsigned short* __restrict__ out, int R, int C) {
  __shared__ float tile[32][33];
  int tx = threadIdx.x, ty = threadIdx.y;
  int c0 = blockIdx.x * 32, r0 = blockIdx.y * 32;
  #pragma unroll
  for (int i = 0; i < 32; i += 8)
    tile[ty + i][tx] = in[(size_t)(r0 + ty + i) * C + c0 + tx];
  __syncthreads();
  #pragma unroll
  for (int i = 0; i < 32; i += 8)
    out[(size_t)(c0 + ty + i) * R + r0 + tx] = f2bf(tile[tx][ty + i]);
}

// ====================== persistent-kernel building blocks ==================
// stage a [nrows x KSRC] bf16 panel into LDS, row stride rowStrideB bytes,
// segment byte offset segOffB within the row, XOR-swizzled: byte ^= (row&7)<<4.
template<int KSRC>
__device__ __forceinline__ void stage_panel(const unsigned short* __restrict__ src,
                                            int nrows, char* lds, int rowStrideB,
                                            int segOffB) {
  const int chunksPerRow = KSRC / 8;          // 16B chunks per row
  for (int c = threadIdx.x; c < nrows * chunksPerRow; c += 256) {
    const int row = c / chunksPerRow;
    const int cc = c - row * chunksPerRow;
    short8 v = *(const short8*)(src + (size_t)row * KSRC + cc * 8);
    const int b = (segOffB + cc * 16) ^ ((row & 7) << 4);
    *(short8*)(lds + (size_t)row * rowStrideB + b) = v;
  }
}

// K-loop: acc[4][NI] += A[64 rows x K] @ B_panel^T; A direct from global (L2),
// B fragments from swizzled LDS. No barriers inside: LDS is read-only here.
template<int KCH, int NI>
__device__ __forceinline__ void kloop(const unsigned short* __restrict__ Ab, int K,
                                      const char* __restrict__ ldsB, int rowStrideB,
                                      int segOffB, f32x4 (&acc)[4][NI],
                                      int lr, int kb) {
  #pragma unroll 4
  for (int kc = 0; kc < KCH; ++kc) {
    short8 af[4];
    #pragma unroll
    for (int mi = 0; mi < 4; ++mi)
      af[mi] = *(const short8*)(Ab + (size_t)(mi * 16 + lr) * K + kc * 32 + kb * 8);
    short8 bfv[NI];
    #pragma unroll
    for (int ni = 0; ni < NI; ++ni) {
      const int row = ni * 16 + lr;
      const int b = (segOffB + kc * 64 + kb * 16) ^ ((row & 7) << 4);
      bfv[ni] = *(const short8*)(ldsB + (size_t)row * rowStrideB + b);
    }
    #pragma unroll
    for (int mi = 0; mi < 4; ++mi)
      #pragma unroll
      for (int ni = 0; ni < NI; ++ni)
        acc[mi][ni] = __builtin_amdgcn_mfma_f32_16x16x32_bf16(af[mi], bfv[ni],
                                                              acc[mi][ni], 0, 0, 0);
  }
}

// 16-block band barrier: monotonic counter, device-scope; __threadfence pairs
// give release/acquire coherence (L1 inv + L2 wb/inv) across CUs (and XCDs,
// if the band->XCD mapping assumption fails). Bounded spin: never silently
// hangs the harness.
__device__ __forceinline__ void band_barrier(unsigned* ctr, unsigned target) {
  __syncthreads();
  if (threadIdx.x == 0) {
    __threadfence();
    __hip_atomic_fetch_add(ctr, 1u, __ATOMIC_RELAXED, __HIP_MEMORY_SCOPE_AGENT);
    unsigned spins = 0;
    while (__hip_atomic_load(ctr, __ATOMIC_RELAXED, __HIP_MEMORY_SCOPE_AGENT) < target) {
      __builtin_amdgcn_s_sleep(2);
      if (++spins > 0x8000000u) break;   // ~seconds; co-residency violated
    }
    __threadfence();
  }
  __syncthreads();
}

// ============================ persistent kernel ============================
// grid = 256 blocks (1/CU via 128KB LDS), block = 256 threads / 4 waves.
// Block (mb,nb): 256-row band x 64-col panel. Band blocks share id&7 -> XCD.
__global__ __launch_bounds__(256, 1) void fused_kernel(
    const unsigned short* __restrict__ xsb, const unsigned short* __restrict__ usb,
    const unsigned short* __restrict__ abt, const unsigned short* __restrict__ b1bt,
    const unsigned short* __restrict__ b2bt, const unsigned short* __restrict__ c2bt,
    const unsigned short* __restrict__ d3bt,
    unsigned short* __restrict__ qa, unsigned short* __restrict__ qb,
    float* __restrict__ out, unsigned* __restrict__ bars)
{
  __shared__ alignas(16) char lds[131072];   // 128 KB -> 1 block/CU
  const int id = blockIdx.x;
  const int t = threadIdx.x;

  const int mb = (id & 7) * 2 + ((id >> 3) & 1);   // band 0..15
  const int nb = id >> 4;                          // panel 0..15
  const int wave = t >> 6;
  const int lane = t & 63;
  const int lr = lane & 15;
  const int kbq = lane >> 4;
  const int grow0 = mb * 256 + wave * 64;          // wave's first global row
  unsigned* bandctr = bars + 32 * mb;              // 128B apart per band
  unsigned epoch = 0;

  // ---- Phase 1: xc = xs @ C2_T panel (kept in regs), q1 = tanh(xc) --------
  stage_panel<STATE>(c2bt + (size_t)(nb * 64) * STATE, 64, lds, STATE * 2, 0);
  __syncthreads();
  f32x4 acc[4][4];
  #pragma unroll
  for (int i = 0; i < 4; ++i)
    #pragma unroll
    for (int j = 0; j < 4; ++j) acc[i][j] = (f32x4){0.f, 0.f, 0.f, 0.f};
  kloop<STATE / 32, 4>(xsb + (size_t)grow0 * STATE, STATE, lds, STATE * 2, 0,
                       acc, lr, kbq);
  float xc[4][4][4];
  #pragma unroll
  for (int mi = 0; mi < 4; ++mi)
    #pragma unroll
    for (int ni = 0; ni < 4; ++ni)
      #pragma unroll
      for (int r = 0; r < 4; ++r) {
        const float v = acc[mi][ni][r];
        xc[mi][ni][r] = v;
        qa[(size_t)(grow0 + mi * 16 + kbq * 4 + r) * NONLIN + nb * 64 + ni * 16 + lr]
            = f2bf(fast_tanh(v));
      }
  __syncthreads();   // all waves done reading the C2 panel from LDS
  stage_panel<NONLIN>(d3bt + (size_t)(nb * 64) * NONLIN, 64, lds, NONLIN * 2, 0);
  band_barrier(bandctr, ++epoch * 16u);   // q1 visible band-wide; D3 staged

  // ---- Phase 2: fixed-point iterations (D3 panel resident in LDS) ---------
  const unsigned short* qp = qa;
  unsigned short* qw = qb;
  for (int it = 0; it < NMAPS - 1; ++it) {
    #pragma unroll
    for (int i = 0; i < 4; ++i)
      #pragma unroll
      for (int j = 0; j < 4; ++j) acc[i][j] = (f32x4){0.f, 0.f, 0.f, 0.f};
    kloop<NONLIN / 32, 4>(qp + (size_t)grow0 * NONLIN, NONLIN, lds, NONLIN * 2, 0,
                          acc, lr, kbq);
    #pragma unroll
    for (int mi = 0; mi < 4; ++mi)
      #pragma unroll
      for (int ni = 0; ni < 4; ++ni)
        #pragma unroll
        for (int r = 0; r < 4; ++r)
          qw[(size_t)(grow0 + mi * 16 + kbq * 4 + r) * NONLIN + nb * 64 + ni * 16 + lr]
              = f2bf(fast_tanh(xc[mi][ni][r] + acc[mi][ni][r]));
    band_barrier(bandctr, ++epoch * 16u);
    const unsigned short* tmp = qp; qp = qw; qw = (unsigned short*)tmp;
  }

  // ---- Phase 3: out = xs@A_T + q*@B1_T + us@B2_T  (256x32 tiles) ----------
  // concat B panels [32 rows x (512|1024|256)] in LDS, row stride 3584B
  stage_panel<STATE >(abt  + (size_t)(nb * 32) * STATE,  32, lds, 3584, 0);
  stage_panel<NONLIN>(b1bt + (size_t)(nb * 32) * NONLIN, 32, lds, 3584, 1024);
  stage_panel<ACTION>(b2bt + (size_t)(nb * 32) * ACTION, 32, lds, 3584, 3072);
  __syncthreads();
  f32x4 acc2[4][2];
  #pragma unroll
  for (int i = 0; i < 4; ++i)
    #pragma unroll
    for (int j = 0; j < 2; ++j) acc2[i][j] = (f32x4){0.f, 0.f, 0.f, 0.f};
  kloop<STATE / 32, 2>(xsb + (size_t)grow0 * STATE, STATE, lds, 3584, 0,
                       acc2, lr, kbq);
  kloop<NONLIN / 32, 2>(qp + (size_t)grow0 * NONLIN, NONLIN, lds, 3584, 1024,
                        acc2, lr, kbq);
  kloop<ACTION / 32, 2>(usb + (size_t)grow0 * ACTION, ACTION, lds, 3584, 3072,
                        acc2, lr, kbq);
  #pragma unroll
  for (int mi = 0; mi < 4; ++mi)
    #pragma unroll
    for (int ni = 0; ni < 2; ++ni)
      #pragma unroll
      for (int r = 0; r < 4; ++r)
        out[(size_t)(grow0 + mi * 16 + kbq * 4 + r) * STATE + nb * 32 + ni * 16 + lr]
            = acc2[mi][ni][r];
}

extern "C" void kernel_launch(void* const* d_in, const int* in_sizes, int n_in,
                              void* d_out, int out_size, void* d_ws, size_t ws_size,
                              hipStream_t stream) {
  const float* xs   = (const float*)d_in[0];
  const float* us   = (const float*)d_in[1];
  const float* A_T  = (const float*)d_in[2];
  const float* B1_T = (const float*)d_in[3];
  const float* B2_T = (const float*)d_in[4];
  const float* C2_T = (const float*)d_in[5];
  const float* D3_T = (const float*)d_in[6];
  float* outp = (float*)d_out;

  size_t off = 0;
  auto take = [&](size_t b) {
    void* p = (char*)d_ws + off;
    off += (b + 255) & ~(size_t)255;
    return p;
  };
  unsigned*       bars = (unsigned*)take(4096);
  unsigned short* qa   = (unsigned short*)take((size_t)BATCH * NONLIN * 2);
  unsigned short* qb   = (unsigned short*)take((size_t)BATCH * NONLIN * 2);
  unsigned short* xsb  = (unsigned short*)take((size_t)BATCH * STATE * 2);
  unsigned short* usb  = (unsigned short*)take((size_t)BATCH * ACTION * 2);
  unsigned short* abt  = (unsigned short*)take((size_t)STATE * STATE * 2);
  unsigned short* b1bt = (unsigned short*)take((size_t)STATE * NONLIN * 2);
  unsigned short* b2bt = (unsigned short*)take((size_t)STATE * ACTION * 2);
  unsigned short* c2bt = (unsigned short*)take((size_t)NONLIN * STATE * 2);
  unsigned short* d3bt = (unsigned short*)take((size_t)NONLIN * NONLIN * 2);
  (void)ws_size; (void)in_sizes; (void)n_in; (void)out_size;

  // barrier counters must start at 0 every call (ws is poisoned, not restored)
  hipMemsetAsync(bars, 0, 4096, stream);

  // prologue: activations -> bf16; weights -> bf16 transposed to [N][K]
  {
    int n4 = BATCH * STATE / 4;
    convert_kernel<<<n4 / 256, 256, 0, stream>>>(xs, xsb, n4);
  }
  {
    int n4 = BATCH * ACTION / 4;
    convert_kernel<<<n4 / 256, 256, 0, stream>>>(us, usb, n4);
  }
  transpose_kernel<<<dim3(STATE / 32, STATE / 32),   dim3(32, 8), 0, stream>>>(A_T,  abt,  STATE,  STATE);
  transpose_kernel<<<dim3(STATE / 32, NONLIN / 32),  dim3(32, 8), 0, stream>>>(B1_T, b1bt, NONLIN, STATE);
  transpose_kernel<<<dim3(STATE / 32, ACTION / 32),  dim3(32, 8), 0, stream>>>(B2_T, b2bt, ACTION, STATE);
  transpose_kernel<<<dim3(NONLIN / 32, STATE / 32),  dim3(32, 8), 0, stream>>>(C2_T, c2bt, STATE,  NONLIN);
  transpose_kernel<<<dim3(NONLIN / 32, NONLIN / 32), dim3(32, 8), 0, stream>>>(D3_T, d3bt, NONLIN, NONLIN);

  // persistent kernel: phases 1-3 with band-local software barriers
  fused_kernel<<<dim3(256), dim3(256), 0, stream>>>(
      xsb, usb, abt, b1bt, b2bt, c2bt, d3bt, qa, qb, outp, bars);
}

// Round 5
// 314.804 us; speedup vs baseline: 1.6309x; 1.6309x over previous
//
#include <hip/hip_runtime.h>
#include <cstdint>
#include <cstddef>

#define BATCH 4096
#define STATE 512
#define NONLIN 1024
#define ACTION 256
#define NMAPS 12   // tanh-map applications; contraction L~0.58 (R4: same absmax as 18)

typedef __attribute__((ext_vector_type(8))) short short8;
typedef __attribute__((ext_vector_type(4))) float f32x4;

__device__ __forceinline__ unsigned short f2bf(float f) {
  unsigned u = __float_as_uint(f);
  return (unsigned short)((u + 0x7FFFu + ((u >> 16) & 1u)) >> 16);
}
__device__ __forceinline__ float bf2f(unsigned short b) {
  return __uint_as_float((unsigned)b << 16);
}
__device__ __forceinline__ float fast_tanh(float x) {
  return 1.0f - 2.0f / (__expf(2.0f * x) + 1.0f);
}

// ============================ prologue (2 launches) ========================
__global__ void convert_both_kernel(const float* __restrict__ xs,
                                    const float* __restrict__ us,
                                    unsigned short* __restrict__ xsb,
                                    unsigned short* __restrict__ usb) {
  const int n1 = BATCH * STATE / 4;
  const int n2 = BATCH * ACTION / 4;
  int i = blockIdx.x * 256 + threadIdx.x;
  const float* in; unsigned short* out;
  if (i < n1) { in = xs; out = xsb; }
  else { i -= n1; if (i >= n2) return; in = us; out = usb; }
  float4 v = reinterpret_cast<const float4*>(in)[i];
  ushort4 o;
  o.x = f2bf(v.x); o.y = f2bf(v.y); o.z = f2bf(v.z); o.w = f2bf(v.w);
  reinterpret_cast<ushort4*>(out)[i] = o;
}

// all 5 weight transposes in one launch; in [R][C] f32 -> out [C][R] bf16
__global__ void transpose_all_kernel(
    const float* __restrict__ A_T, const float* __restrict__ B1_T,
    const float* __restrict__ B2_T, const float* __restrict__ C2_T,
    const float* __restrict__ D3_T,
    unsigned short* __restrict__ abt, unsigned short* __restrict__ b1bt,
    unsigned short* __restrict__ b2bt, unsigned short* __restrict__ c2bt,
    unsigned short* __restrict__ d3bt) {
  __shared__ float tile[32][33];
  int g = blockIdx.x;
  const float* in; unsigned short* out; int R, C, li;
  if (g < 256)       { in = A_T;  out = abt;  R = STATE;  C = STATE;  li = g; }
  else if (g < 768)  { in = B1_T; out = b1bt; R = NONLIN; C = STATE;  li = g - 256; }
  else if (g < 896)  { in = B2_T; out = b2bt; R = ACTION; C = STATE;  li = g - 768; }
  else if (g < 1408) { in = C2_T; out = c2bt; R = STATE;  C = NONLIN; li = g - 896; }
  else               { in = D3_T; out = d3bt; R = NONLIN; C = NONLIN; li = g - 1408; }
  const int ntx = C / 32;
  const int c0 = (li % ntx) * 32, r0 = (li / ntx) * 32;
  const int tx = threadIdx.x, ty = threadIdx.y;
  #pragma unroll
  for (int i = 0; i < 32; i += 8)
    tile[ty + i][tx] = in[(size_t)(r0 + ty + i) * C + c0 + tx];
  __syncthreads();
  #pragma unroll
  for (int i = 0; i < 32; i += 8)
    out[(size_t)(c0 + ty + i) * R + r0 + tx] = f2bf(tile[tx][ty + i]);
}

// ============================ GEMM building blocks =========================
// 256-B swizzle (64-bank hypothesis): byte ^= (row&15)<<4. Applied on both
// the LDS write (stage) and the LDS read (kloop) — same involution.
template<int KSRC, int NT>
__device__ __forceinline__ void stage_panel(const unsigned short* __restrict__ src,
                                            int nrows, char* lds, int rowStrideB,
                                            int segOffB) {
  const int chunksPerRow = KSRC / 8;          // 16B chunks per row
  for (int c = threadIdx.x; c < nrows * chunksPerRow; c += NT) {
    const int row = c / chunksPerRow;
    const int cc = c - row * chunksPerRow;
    short8 v = *(const short8*)(src + (size_t)row * KSRC + cc * 8);
    const int b = segOffB + ((cc * 16) ^ ((row & 15) << 4));
    *(short8*)(lds + (size_t)row * rowStrideB + b) = v;
  }
}

// acc[MI][NI] += A[MI*16 rows x K] @ B_panel^T; A streamed from global (L2)
// with depth-1 prefetch, B fragments from swizzled LDS. No barriers inside.
template<int KCH, int MI, int NI>
__device__ __forceinline__ void kloop(const unsigned short* __restrict__ Ab, int K,
                                      const char* __restrict__ ldsB, int rowStrideB,
                                      int segOffB, f32x4 (&acc)[MI][NI],
                                      int lr, int kb) {
  short8 a_cur[MI], a_nxt[MI];
  #pragma unroll
  for (int mi = 0; mi < MI; ++mi)
    a_cur[mi] = *(const short8*)(Ab + (size_t)(mi * 16 + lr) * K + kb * 8);
  #pragma unroll 4
  for (int kc = 0; kc < KCH; ++kc) {
    if (kc + 1 < KCH) {
      #pragma unroll
      for (int mi = 0; mi < MI; ++mi)
        a_nxt[mi] = *(const short8*)(Ab + (size_t)(mi * 16 + lr) * K
                                     + (kc + 1) * 32 + kb * 8);
    }
    short8 bfv[NI];
    #pragma unroll
    for (int ni = 0; ni < NI; ++ni) {
      const int row = ni * 16 + lr;
      const int b = segOffB + ((kc * 64 + kb * 16) ^ ((row & 15) << 4));
      bfv[ni] = *(const short8*)(ldsB + (size_t)row * rowStrideB + b);
    }
    #pragma unroll
    for (int mi = 0; mi < MI; ++mi)
      #pragma unroll
      for (int ni = 0; ni < NI; ++ni)
        acc[mi][ni] = __builtin_amdgcn_mfma_f32_16x16x32_bf16(a_cur[mi], bfv[ni],
                                                              acc[mi][ni], 0, 0, 0);
    #pragma unroll
    for (int mi = 0; mi < MI; ++mi) a_cur[mi] = a_nxt[mi];
  }
}

// block geometry: grid 256, 512 threads / 8 waves; band mb (256 rows) pinned
// to XCD id&7 (perf heuristic only), panel nb. Wave owns 32 rows.
#define TILE_IDX()                                          \
  const int id = blockIdx.x;                                \
  const int mb = (id & 7) * 2 + ((id >> 3) & 1);            \
  const int nb = id >> 4;                                   \
  const int t = threadIdx.x;                                \
  const int wave = t >> 6;                                  \
  const int lane = t & 63;                                  \
  const int lr = lane & 15;                                 \
  const int kbq = lane >> 4;                                \
  const int grow0 = mb * 256 + wave * 32;

// ---- xc = xs @ C2_T panel; xcb = bf16(xc); q0 = tanh(xc) ------------------
__global__ __launch_bounds__(512) void gemm_xc_kernel(
    const unsigned short* __restrict__ xsb, const unsigned short* __restrict__ c2bt,
    unsigned short* __restrict__ xcb, unsigned short* __restrict__ q0) {
  __shared__ alignas(16) char lds[65536];     // 64 rows x 1024 B
  TILE_IDX();
  stage_panel<STATE, 512>(c2bt + (size_t)(nb * 64) * STATE, 64, lds, STATE * 2, 0);
  __syncthreads();
  f32x4 acc[2][4];
  #pragma unroll
  for (int i = 0; i < 2; ++i)
    #pragma unroll
    for (int j = 0; j < 4; ++j) acc[i][j] = (f32x4){0.f, 0.f, 0.f, 0.f};
  kloop<STATE / 32, 2, 4>(xsb + (size_t)grow0 * STATE, STATE, lds, STATE * 2, 0,
                          acc, lr, kbq);
  #pragma unroll
  for (int mi = 0; mi < 2; ++mi)
    #pragma unroll
    for (int ni = 0; ni < 4; ++ni)
      #pragma unroll
      for (int r = 0; r < 4; ++r) {
        const int row = grow0 + mi * 16 + kbq * 4 + r;
        const int col = nb * 64 + ni * 16 + lr;
        const size_t idx = (size_t)row * NONLIN + col;
        const float v = acc[mi][ni][r];
        xcb[idx] = f2bf(v);
        q0[idx] = f2bf(fast_tanh(v));
      }
}

// ---- one fixed-point step: qout = tanh(xc + qin @ D3_T panel) -------------
__global__ __launch_bounds__(512) void gemm_iter_kernel(
    const unsigned short* __restrict__ qin, const unsigned short* __restrict__ d3bt,
    const unsigned short* __restrict__ xcb, unsigned short* __restrict__ qout) {
  __shared__ alignas(16) char lds[131072];    // 64 rows x 2048 B
  TILE_IDX();
  stage_panel<NONLIN, 512>(d3bt + (size_t)(nb * 64) * NONLIN, 64, lds, NONLIN * 2, 0);
  __syncthreads();
  f32x4 acc[2][4];
  #pragma unroll
  for (int i = 0; i < 2; ++i)
    #pragma unroll
    for (int j = 0; j < 4; ++j) acc[i][j] = (f32x4){0.f, 0.f, 0.f, 0.f};
  kloop<NONLIN / 32, 2, 4>(qin + (size_t)grow0 * NONLIN, NONLIN, lds, NONLIN * 2, 0,
                           acc, lr, kbq);
  #pragma unroll
  for (int mi = 0; mi < 2; ++mi)
    #pragma unroll
    for (int ni = 0; ni < 4; ++ni)
      #pragma unroll
      for (int r = 0; r < 4; ++r) {
        const int row = grow0 + mi * 16 + kbq * 4 + r;
        const int col = nb * 64 + ni * 16 + lr;
        const size_t idx = (size_t)row * NONLIN + col;
        qout[idx] = f2bf(fast_tanh(bf2f(xcb[idx]) + acc[mi][ni][r]));
      }
}

// ---- out = xs@A_T + q*@B1_T + us@B2_T  (f32, N=512; 256x32 tiles) ---------
__global__ __launch_bounds__(512) void gemm_out_kernel(
    const unsigned short* __restrict__ xsb, const unsigned short* __restrict__ abt,
    const unsigned short* __restrict__ q,   const unsigned short* __restrict__ b1bt,
    const unsigned short* __restrict__ usb, const unsigned short* __restrict__ b2bt,
    float* __restrict__ out) {
  __shared__ alignas(16) char lds[114688];    // 32 rows x 3584 B (A|B1|B2 concat)
  TILE_IDX();
  stage_panel<STATE,  512>(abt  + (size_t)(nb * 32) * STATE,  32, lds, 3584, 0);
  stage_panel<NONLIN, 512>(b1bt + (size_t)(nb * 32) * NONLIN, 32, lds, 3584, 1024);
  stage_panel<ACTION, 512>(b2bt + (size_t)(nb * 32) * ACTION, 32, lds, 3584, 3072);
  __syncthreads();
  f32x4 acc[2][2];
  #pragma unroll
  for (int i = 0; i < 2; ++i)
    #pragma unroll
    for (int j = 0; j < 2; ++j) acc[i][j] = (f32x4){0.f, 0.f, 0.f, 0.f};
  kloop<STATE / 32, 2, 2>(xsb + (size_t)grow0 * STATE, STATE, lds, 3584, 0,
                          acc, lr, kbq);
  kloop<NONLIN / 32, 2, 2>(q + (size_t)grow0 * NONLIN, NONLIN, lds, 3584, 1024,
                           acc, lr, kbq);
  kloop<ACTION / 32, 2, 2>(usb + (size_t)grow0 * ACTION, ACTION, lds, 3584, 3072,
                           acc, lr, kbq);
  #pragma unroll
  for (int mi = 0; mi < 2; ++mi)
    #pragma unroll
    for (int ni = 0; ni < 2; ++ni)
      #pragma unroll
      for (int r = 0; r < 4; ++r) {
        const int row = grow0 + mi * 16 + kbq * 4 + r;
        const int col = nb * 32 + ni * 16 + lr;
        out[(size_t)row * STATE + col] = acc[mi][ni][r];
      }
}

extern "C" void kernel_launch(void* const* d_in, const int* in_sizes, int n_in,
                              void* d_out, int out_size, void* d_ws, size_t ws_size,
                              hipStream_t stream) {
  const float* xs   = (const float*)d_in[0];
  const float* us   = (const float*)d_in[1];
  const float* A_T  = (const float*)d_in[2];
  const float* B1_T = (const float*)d_in[3];
  const float* B2_T = (const float*)d_in[4];
  const float* C2_T = (const float*)d_in[5];
  const float* D3_T = (const float*)d_in[6];
  float* outp = (float*)d_out;

  size_t off = 0;
  auto take = [&](size_t b) {
    void* p = (char*)d_ws + off;
    off += (b + 255) & ~(size_t)255;
    return p;
  };
  unsigned short* xcb  = (unsigned short*)take((size_t)BATCH * NONLIN * 2);
  unsigned short* qa   = (unsigned short*)take((size_t)BATCH * NONLIN * 2);
  unsigned short* qb   = (unsigned short*)take((size_t)BATCH * NONLIN * 2);
  unsigned short* xsb  = (unsigned short*)take((size_t)BATCH * STATE * 2);
  unsigned short* usb  = (unsigned short*)take((size_t)BATCH * ACTION * 2);
  unsigned short* abt  = (unsigned short*)take((size_t)STATE * STATE * 2);
  unsigned short* b1bt = (unsigned short*)take((size_t)STATE * NONLIN * 2);
  unsigned short* b2bt = (unsigned short*)take((size_t)STATE * ACTION * 2);
  unsigned short* c2bt = (unsigned short*)take((size_t)NONLIN * STATE * 2);
  unsigned short* d3bt = (unsigned short*)take((size_t)NONLIN * NONLIN * 2);
  (void)ws_size; (void)in_sizes; (void)n_in; (void)out_size;

  // prologue: 2 launches
  convert_both_kernel<<<dim3(3072), dim3(256), 0, stream>>>(xs, us, xsb, usb);
  transpose_all_kernel<<<dim3(2432), dim3(32, 8), 0, stream>>>(
      A_T, B1_T, B2_T, C2_T, D3_T, abt, b1bt, b2bt, c2bt, d3bt);

  // fixed-point map 1: xc + q0
  gemm_xc_kernel<<<dim3(256), dim3(512), 0, stream>>>(xsb, c2bt, xcb, qa);

  // maps 2..NMAPS
  unsigned short* qin = qa;
  unsigned short* qout = qb;
  for (int it = 0; it < NMAPS - 1; ++it) {
    gemm_iter_kernel<<<dim3(256), dim3(512), 0, stream>>>(qin, d3bt, xcb, qout);
    unsigned short* tmp = qin; qin = qout; qout = tmp;
  }

  // out = xs@A_T + q*@B1_T + us@B2_T
  gemm_out_kernel<<<dim3(256), dim3(512), 0, stream>>>(
      xsb, abt, qin, b1bt, usb, b2bt, outp);
}

// Round 6
// 302.314 us; speedup vs baseline: 1.6983x; 1.0413x over previous
//
#include <hip/hip_runtime.h>
#include <cstdint>
#include <cstddef>

#define BATCH 4096
#define STATE 512
#define NONLIN 1024
#define ACTION 256
#define NMAPS 11   // tanh-map applications; truncation ~0.58^11*2.4 ~ 0.006 << 0.0925

typedef __attribute__((ext_vector_type(8))) short short8;
typedef __attribute__((ext_vector_type(4))) float f32x4;

__device__ __forceinline__ unsigned short f2bf(float f) {
  unsigned u = __float_as_uint(f);
  return (unsigned short)((u + 0x7FFFu + ((u >> 16) & 1u)) >> 16);
}
__device__ __forceinline__ float bf2f(unsigned short b) {
  return __uint_as_float((unsigned)b << 16);
}
__device__ __forceinline__ float fast_tanh(float x) {
  return 1.0f - 2.0f / (__expf(2.0f * x) + 1.0f);
}

// ============================ prologue (2 launches) ========================
__global__ void convert_both_kernel(const float* __restrict__ xs,
                                    const float* __restrict__ us,
                                    unsigned short* __restrict__ xsb,
                                    unsigned short* __restrict__ usb) {
  const int n1 = BATCH * STATE / 4;
  const int n2 = BATCH * ACTION / 4;
  int i = blockIdx.x * 256 + threadIdx.x;
  const float* in; unsigned short* out;
  if (i < n1) { in = xs; out = xsb; }
  else { i -= n1; if (i >= n2) return; in = us; out = usb; }
  float4 v = reinterpret_cast<const float4*>(in)[i];
  ushort4 o;
  o.x = f2bf(v.x); o.y = f2bf(v.y); o.z = f2bf(v.z); o.w = f2bf(v.w);
  reinterpret_cast<ushort4*>(out)[i] = o;
}

// all 5 weight transposes in one launch; in [R][C] f32 -> out [C][R] bf16
__global__ void transpose_all_kernel(
    const float* __restrict__ A_T, const float* __restrict__ B1_T,
    const float* __restrict__ B2_T, const float* __restrict__ C2_T,
    const float* __restrict__ D3_T,
    unsigned short* __restrict__ abt, unsigned short* __restrict__ b1bt,
    unsigned short* __restrict__ b2bt, unsigned short* __restrict__ c2bt,
    unsigned short* __restrict__ d3bt) {
  __shared__ float tile[32][33];
  int g = blockIdx.x;
  const float* in; unsigned short* out; int R, C, li;
  if (g < 256)       { in = A_T;  out = abt;  R = STATE;  C = STATE;  li = g; }
  else if (g < 768)  { in = B1_T; out = b1bt; R = NONLIN; C = STATE;  li = g - 256; }
  else if (g < 896)  { in = B2_T; out = b2bt; R = ACTION; C = STATE;  li = g - 768; }
  else if (g < 1408) { in = C2_T; out = c2bt; R = STATE;  C = NONLIN; li = g - 896; }
  else               { in = D3_T; out = d3bt; R = NONLIN; C = NONLIN; li = g - 1408; }
  const int ntx = C / 32;
  const int c0 = (li % ntx) * 32, r0 = (li / ntx) * 32;
  const int tx = threadIdx.x, ty = threadIdx.y;
  #pragma unroll
  for (int i = 0; i < 32; i += 8)
    tile[ty + i][tx] = in[(size_t)(r0 + ty + i) * C + c0 + tx];
  __syncthreads();
  #pragma unroll
  for (int i = 0; i < 32; i += 8)
    out[(size_t)(c0 + ty + i) * R + r0 + tx] = f2bf(tile[tx][ty + i]);
}

// ============================ GEMM building blocks =========================
// 256-B-window swizzle: byte ^= (row&15)<<4, same involution on write & read.
template<int KSRC, int NT>
__device__ __forceinline__ void stage_panel(const unsigned short* __restrict__ src,
                                            int nrows, char* lds, int rowStrideB,
                                            int segOffB) {
  const int chunksPerRow = KSRC / 8;          // 16B chunks per row
  for (int c = threadIdx.x; c < nrows * chunksPerRow; c += NT) {
    const int row = c / chunksPerRow;
    const int cc = c - row * chunksPerRow;
    short8 v = *(const short8*)(src + (size_t)row * KSRC + cc * 8);
    const int b = segOffB + ((cc * 16) ^ ((row & 15) << 4));
    *(short8*)(lds + (size_t)row * rowStrideB + b) = v;
  }
}

// acc[MI][NI] += A[MI*16 rows x K] @ B_panel^T; A streamed from global (L2)
// with depth-PD register prefetch (fully unrolled -> static indices), B from
// swizzled LDS. No barriers inside: LDS is read-only here.
template<int KCH, int MI, int NI, int PD>
__device__ __forceinline__ void kloop(const unsigned short* __restrict__ Ab, int K,
                                      const char* __restrict__ ldsB, int rowStrideB,
                                      int segOffB, f32x4 (&acc)[MI][NI],
                                      int lr, int kb) {
  static_assert(KCH >= PD, "pipeline deeper than K");
  short8 a_buf[PD][MI];
  #pragma unroll
  for (int d = 0; d < PD; ++d)
    #pragma unroll
    for (int mi = 0; mi < MI; ++mi)
      a_buf[d][mi] = *(const short8*)(Ab + (size_t)(mi * 16 + lr) * K
                                      + d * 32 + kb * 8);
  #pragma unroll
  for (int kc = 0; kc < KCH; ++kc) {
    short8 bfv[NI];
    #pragma unroll
    for (int ni = 0; ni < NI; ++ni) {
      const int row = ni * 16 + lr;
      const int b = segOffB + ((kc * 64 + kb * 16) ^ ((row & 15) << 4));
      bfv[ni] = *(const short8*)(ldsB + (size_t)row * rowStrideB + b);
    }
    #pragma unroll
    for (int mi = 0; mi < MI; ++mi)
      #pragma unroll
      for (int ni = 0; ni < NI; ++ni)
        acc[mi][ni] = __builtin_amdgcn_mfma_f32_16x16x32_bf16(a_buf[kc % PD][mi],
                                                              bfv[ni],
                                                              acc[mi][ni], 0, 0, 0);
    if (kc + PD < KCH) {
      #pragma unroll
      for (int mi = 0; mi < MI; ++mi)
        a_buf[kc % PD][mi] = *(const short8*)(Ab + (size_t)(mi * 16 + lr) * K
                                              + (kc + PD) * 32 + kb * 8);
    }
  }
}

// block geometry: grid 256, 512 threads / 8 waves; band mb (256 rows) pinned
// to XCD id&7 (perf heuristic only), panel nb. Wave owns 32 rows.
#define TILE_IDX()                                          \
  const int id = blockIdx.x;                                \
  const int mb = (id & 7) * 2 + ((id >> 3) & 1);            \
  const int nb = id >> 4;                                   \
  const int t = threadIdx.x;                                \
  const int wave = t >> 6;                                  \
  const int lane = t & 63;                                  \
  const int lr = lane & 15;                                 \
  const int kbq = lane >> 4;                                \
  const int grow0 = mb * 256 + wave * 32;

// ---- xc = xs @ C2_T panel; xcf = fragment-layout bf16(xc); q0 = tanh(xc) --
// xcf layout: [block id][thread][32] matching (mi*16 + ni*4 + r) order, so the
// iter kernels (same grid geometry) reload xc with 4 coalesced 16B loads.
__global__ __launch_bounds__(512) void gemm_xc_kernel(
    const unsigned short* __restrict__ xsb, const unsigned short* __restrict__ c2bt,
    unsigned short* __restrict__ xcf, unsigned short* __restrict__ q0) {
  __shared__ alignas(16) char lds[65536];     // 64 rows x 1024 B
  TILE_IDX();
  stage_panel<STATE, 512>(c2bt + (size_t)(nb * 64) * STATE, 64, lds, STATE * 2, 0);
  __syncthreads();
  f32x4 acc[2][4];
  #pragma unroll
  for (int i = 0; i < 2; ++i)
    #pragma unroll
    for (int j = 0; j < 4; ++j) acc[i][j] = (f32x4){0.f, 0.f, 0.f, 0.f};
  kloop<STATE / 32, 2, 4, 4>(xsb + (size_t)grow0 * STATE, STATE, lds, STATE * 2, 0,
                             acc, lr, kbq);
  unsigned short frag[32];
  #pragma unroll
  for (int mi = 0; mi < 2; ++mi)
    #pragma unroll
    for (int ni = 0; ni < 4; ++ni)
      #pragma unroll
      for (int r = 0; r < 4; ++r) {
        const int row = grow0 + mi * 16 + kbq * 4 + r;
        const int col = nb * 64 + ni * 16 + lr;
        const float v = acc[mi][ni][r];
        frag[mi * 16 + ni * 4 + r] = f2bf(v);
        q0[(size_t)row * NONLIN + col] = f2bf(fast_tanh(v));
      }
  unsigned short* xp = xcf + ((size_t)id * 512 + t) * 32;
  #pragma unroll
  for (int k = 0; k < 4; ++k)
    *(short8*)(xp + k * 8) = *(const short8*)(frag + k * 8);
}

// ---- one fixed-point step: qout = tanh(xc + qin @ D3_T panel) -------------
__global__ __launch_bounds__(512) void gemm_iter_kernel(
    const unsigned short* __restrict__ qin, const unsigned short* __restrict__ d3bt,
    const unsigned short* __restrict__ xcf, unsigned short* __restrict__ qout) {
  __shared__ alignas(16) char lds[131072];    // 64 rows x 2048 B
  TILE_IDX();
  stage_panel<NONLIN, 512>(d3bt + (size_t)(nb * 64) * NONLIN, 64, lds, NONLIN * 2, 0);
  __syncthreads();
  f32x4 acc[2][4];
  #pragma unroll
  for (int i = 0; i < 2; ++i)
    #pragma unroll
    for (int j = 0; j < 4; ++j) acc[i][j] = (f32x4){0.f, 0.f, 0.f, 0.f};
  kloop<NONLIN / 32, 2, 4, 4>(qin + (size_t)grow0 * NONLIN, NONLIN, lds,
                              NONLIN * 2, 0, acc, lr, kbq);
  short8 xcv[4];
  const unsigned short* xp = xcf + ((size_t)id * 512 + t) * 32;
  #pragma unroll
  for (int k = 0; k < 4; ++k) xcv[k] = *(const short8*)(xp + k * 8);
  #pragma unroll
  for (int mi = 0; mi < 2; ++mi)
    #pragma unroll
    for (int ni = 0; ni < 4; ++ni)
      #pragma unroll
      for (int r = 0; r < 4; ++r) {
        const int row = grow0 + mi * 16 + kbq * 4 + r;
        const int col = nb * 64 + ni * 16 + lr;
        const int fi = mi * 16 + ni * 4 + r;
        const float xv = bf2f((unsigned short)xcv[fi / 8][fi % 8]);
        qout[(size_t)row * NONLIN + col] = f2bf(fast_tanh(xv + acc[mi][ni][r]));
      }
}

// ---- out = xs@A_T + q*@B1_T + us@B2_T  (f32, N=512; 256x32 tiles) ---------
__global__ __launch_bounds__(512) void gemm_out_kernel(
    const unsigned short* __restrict__ xsb, const unsigned short* __restrict__ abt,
    const unsigned short* __restrict__ q,   const unsigned short* __restrict__ b1bt,
    const unsigned short* __restrict__ usb, const unsigned short* __restrict__ b2bt,
    float* __restrict__ out) {
  __shared__ alignas(16) char lds[114688];    // 32 rows x 3584 B (A|B1|B2 concat)
  TILE_IDX();
  stage_panel<STATE,  512>(abt  + (size_t)(nb * 32) * STATE,  32, lds, 3584, 0);
  stage_panel<NONLIN, 512>(b1bt + (size_t)(nb * 32) * NONLIN, 32, lds, 3584, 1024);
  stage_panel<ACTION, 512>(b2bt + (size_t)(nb * 32) * ACTION, 32, lds, 3584, 3072);
  __syncthreads();
  f32x4 acc[2][2];
  #pragma unroll
  for (int i = 0; i < 2; ++i)
    #pragma unroll
    for (int j = 0; j < 2; ++j) acc[i][j] = (f32x4){0.f, 0.f, 0.f, 0.f};
  kloop<STATE / 32, 2, 2, 4>(xsb + (size_t)grow0 * STATE, STATE, lds, 3584, 0,
                             acc, lr, kbq);
  kloop<NONLIN / 32, 2, 2, 4>(q + (size_t)grow0 * NONLIN, NONLIN, lds, 3584, 1024,
                              acc, lr, kbq);
  kloop<ACTION / 32, 2, 2, 4>(usb + (size_t)grow0 * ACTION, ACTION, lds, 3584, 3072,
                              acc, lr, kbq);
  #pragma unroll
  for (int mi = 0; mi < 2; ++mi)
    #pragma unroll
    for (int ni = 0; ni < 2; ++ni)
      #pragma unroll
      for (int r = 0; r < 4; ++r) {
        const int row = grow0 + mi * 16 + kbq * 4 + r;
        const int col = nb * 32 + ni * 16 + lr;
        out[(size_t)row * STATE + col] = acc[mi][ni][r];
      }
}

extern "C" void kernel_launch(void* const* d_in, const int* in_sizes, int n_in,
                              void* d_out, int out_size, void* d_ws, size_t ws_size,
                              hipStream_t stream) {
  const float* xs   = (const float*)d_in[0];
  const float* us   = (const float*)d_in[1];
  const float* A_T  = (const float*)d_in[2];
  const float* B1_T = (const float*)d_in[3];
  const float* B2_T = (const float*)d_in[4];
  const float* C2_T = (const float*)d_in[5];
  const float* D3_T = (const float*)d_in[6];
  float* outp = (float*)d_out;

  size_t off = 0;
  auto take = [&](size_t b) {
    void* p = (char*)d_ws + off;
    off += (b + 255) & ~(size_t)255;
    return p;
  };
  unsigned short* xcf  = (unsigned short*)take((size_t)BATCH * NONLIN * 2);
  unsigned short* qa   = (unsigned short*)take((size_t)BATCH * NONLIN * 2);
  unsigned short* qb   = (unsigned short*)take((size_t)BATCH * NONLIN * 2);
  unsigned short* xsb  = (unsigned short*)take((size_t)BATCH * STATE * 2);
  unsigned short* usb  = (unsigned short*)take((size_t)BATCH * ACTION * 2);
  unsigned short* abt  = (unsigned short*)take((size_t)STATE * STATE * 2);
  unsigned short* b1bt = (unsigned short*)take((size_t)STATE * NONLIN * 2);
  unsigned short* b2bt = (unsigned short*)take((size_t)STATE * ACTION * 2);
  unsigned short* c2bt = (unsigned short*)take((size_t)NONLIN * STATE * 2);
  unsigned short* d3bt = (unsigned short*)take((size_t)NONLIN * NONLIN * 2);
  (void)ws_size; (void)in_sizes; (void)n_in; (void)out_size;

  // prologue: 2 launches
  convert_both_kernel<<<dim3(3072), dim3(256), 0, stream>>>(xs, us, xsb, usb);
  transpose_all_kernel<<<dim3(2432), dim3(32, 8), 0, stream>>>(
      A_T, B1_T, B2_T, C2_T, D3_T, abt, b1bt, b2bt, c2bt, d3bt);

  // fixed-point map 1: xc + q0
  gemm_xc_kernel<<<dim3(256), dim3(512), 0, stream>>>(xsb, c2bt, xcf, qa);

  // maps 2..NMAPS
  unsigned short* qin = qa;
  unsigned short* qout = qb;
  for (int it = 0; it < NMAPS - 1; ++it) {
    gemm_iter_kernel<<<dim3(256), dim3(512), 0, stream>>>(qin, d3bt, xcf, qout);
    unsigned short* tmp = qin; qin = qout; qout = tmp;
  }

  // out = xs@A_T + q*@B1_T + us@B2_T
  gemm_out_kernel<<<dim3(256), dim3(512), 0, stream>>>(
      xsb, abt, qin, b1bt, usb, b2bt, outp);
}

// Round 7
// 231.644 us; speedup vs baseline: 2.2164x; 1.3051x over previous
//
#include <hip/hip_runtime.h>
#include <cstdint>
#include <cstddef>

#define BATCH 4096
#define STATE 512
#define NONLIN 1024
#define ACTION 256
#define NMAPS 10   // truncation ~0.58^10*2.4 ~ 0.011 (q-scale), < bf16 floor
#define LDQ 1056   // q row stride in elems (2112 B) — breaks 2KB channel aliasing

typedef __attribute__((ext_vector_type(8))) short short8;
typedef __attribute__((ext_vector_type(4))) float f32x4;

__device__ __forceinline__ unsigned short f2bf(float f) {
  unsigned u = __float_as_uint(f);
  return (unsigned short)((u + 0x7FFFu + ((u >> 16) & 1u)) >> 16);
}
__device__ __forceinline__ float bf2f(unsigned short b) {
  return __uint_as_float((unsigned)b << 16);
}
__device__ __forceinline__ float fast_tanh(float x) {
  return 1.0f - 2.0f / (__expf(2.0f * x) + 1.0f);
}

// ============================ prologue (2 launches) ========================
__global__ void convert_both_kernel(const float* __restrict__ xs,
                                    const float* __restrict__ us,
                                    unsigned short* __restrict__ xsb,
                                    unsigned short* __restrict__ usb) {
  const int n1 = BATCH * STATE / 4;
  const int n2 = BATCH * ACTION / 4;
  int i = blockIdx.x * 256 + threadIdx.x;
  const float* in; unsigned short* out;
  if (i < n1) { in = xs; out = xsb; }
  else { i -= n1; if (i >= n2) return; in = us; out = usb; }
  float4 v = reinterpret_cast<const float4*>(in)[i];
  ushort4 o;
  o.x = f2bf(v.x); o.y = f2bf(v.y); o.z = f2bf(v.z); o.w = f2bf(v.w);
  reinterpret_cast<ushort4*>(out)[i] = o;
}

// all 5 weight transposes in one launch; in [R][C] f32 -> out [C][R] bf16
__global__ void transpose_all_kernel(
    const float* __restrict__ A_T, const float* __restrict__ B1_T,
    const float* __restrict__ B2_T, const float* __restrict__ C2_T,
    const float* __restrict__ D3_T,
    unsigned short* __restrict__ abt, unsigned short* __restrict__ b1bt,
    unsigned short* __restrict__ b2bt, unsigned short* __restrict__ c2bt,
    unsigned short* __restrict__ d3bt) {
  __shared__ float tile[32][33];
  int g = blockIdx.x;
  const float* in; unsigned short* out; int R, C, li;
  if (g < 256)       { in = A_T;  out = abt;  R = STATE;  C = STATE;  li = g; }
  else if (g < 768)  { in = B1_T; out = b1bt; R = NONLIN; C = STATE;  li = g - 256; }
  else if (g < 896)  { in = B2_T; out = b2bt; R = ACTION; C = STATE;  li = g - 768; }
  else if (g < 1408) { in = C2_T; out = c2bt; R = STATE;  C = NONLIN; li = g - 896; }
  else               { in = D3_T; out = d3bt; R = NONLIN; C = NONLIN; li = g - 1408; }
  const int ntx = C / 32;
  const int c0 = (li % ntx) * 32, r0 = (li / ntx) * 32;
  const int tx = threadIdx.x, ty = threadIdx.y;
  #pragma unroll
  for (int i = 0; i < 32; i += 8)
    tile[ty + i][tx] = in[(size_t)(r0 + ty + i) * C + c0 + tx];
  __syncthreads();
  #pragma unroll
  for (int i = 0; i < 32; i += 8)
    out[(size_t)(c0 + ty + i) * R + r0 + tx] = f2bf(tile[tx][ty + i]);
}

// ============================ GEMM building blocks =========================
// 256-B-window swizzle: byte ^= (row&15)<<4, same involution on write & read.
template<int KSRC, int NT>
__device__ __forceinline__ void stage_panel(const unsigned short* __restrict__ src,
                                            int nrows, char* lds, int rowStrideB,
                                            int segOffB) {
  const int chunksPerRow = KSRC / 8;          // 16B chunks per row
  for (int c = threadIdx.x; c < nrows * chunksPerRow; c += NT) {
    const int row = c / chunksPerRow;
    const int cc = c - row * chunksPerRow;
    short8 v = *(const short8*)(src + (size_t)row * KSRC + cc * 8);
    const int b = segOffB + ((cc * 16) ^ ((row & 15) << 4));
    *(short8*)(lds + (size_t)row * rowStrideB + b) = v;
  }
}

// acc[MI][NI] += A[MI*16 rows x K] @ B_panel^T; A streamed from global (L2)
// with depth-PD register prefetch (fully unrolled -> static indices), B from
// swizzled LDS. LDA = A row stride in elems (may be padded). No barriers.
template<int KCH, int MI, int NI, int PD>
__device__ __forceinline__ void kloop(const unsigned short* __restrict__ Ab,
                                      int LDA,
                                      const char* __restrict__ ldsB, int rowStrideB,
                                      int segOffB, f32x4 (&acc)[MI][NI],
                                      int lr, int kb) {
  static_assert(KCH >= PD, "pipeline deeper than K");
  short8 a_buf[PD][MI];
  #pragma unroll
  for (int d = 0; d < PD; ++d)
    #pragma unroll
    for (int mi = 0; mi < MI; ++mi)
      a_buf[d][mi] = *(const short8*)(Ab + (size_t)(mi * 16 + lr) * LDA
                                      + d * 32 + kb * 8);
  #pragma unroll
  for (int kc = 0; kc < KCH; ++kc) {
    short8 bfv[NI];
    #pragma unroll
    for (int ni = 0; ni < NI; ++ni) {
      const int row = ni * 16 + lr;
      const int b = segOffB + ((kc * 64 + kb * 16) ^ ((row & 15) << 4));
      bfv[ni] = *(const short8*)(ldsB + (size_t)row * rowStrideB + b);
    }
    #pragma unroll
    for (int mi = 0; mi < MI; ++mi)
      #pragma unroll
      for (int ni = 0; ni < NI; ++ni)
        acc[mi][ni] = __builtin_amdgcn_mfma_f32_16x16x32_bf16(a_buf[kc % PD][mi],
                                                              bfv[ni],
                                                              acc[mi][ni], 0, 0, 0);
    if (kc + PD < KCH) {
      #pragma unroll
      for (int mi = 0; mi < MI; ++mi)
        a_buf[kc % PD][mi] = *(const short8*)(Ab + (size_t)(mi * 16 + lr) * LDA
                                              + (kc + PD) * 32 + kb * 8);
    }
  }
}

// block geometry: grid 256, 512 threads / 8 waves; band mb (256 rows) pinned
// to XCD id&7 (perf heuristic only), panel nb. Wave owns 32 rows.
#define TILE_IDX()                                          \
  const int id = blockIdx.x;                                \
  const int mb = (id & 7) * 2 + ((id >> 3) & 1);            \
  const int nb = id >> 4;                                   \
  const int t = threadIdx.x;                                \
  const int wave = t >> 6;                                  \
  const int lane = t & 63;                                  \
  const int lr = lane & 15;                                 \
  const int kbq = lane >> 4;                                \
  const int grow0 = mb * 256 + wave * 32;

// ---- xc = xs @ C2_T panel; xcf = fragment-layout bf16(xc); q0 = tanh(xc) --
// xcf layout: [block id][thread][32] matching (mi*16 + ni*4 + r) order, so the
// iter kernels (same grid geometry) reload xc with 4 coalesced 16B loads.
__global__ __launch_bounds__(512) void gemm_xc_kernel(
    const unsigned short* __restrict__ xsb, const unsigned short* __restrict__ c2bt,
    unsigned short* __restrict__ xcf, unsigned short* __restrict__ q0) {
  __shared__ alignas(16) char lds[65536];     // 64 rows x 1024 B
  TILE_IDX();
  stage_panel<STATE, 512>(c2bt + (size_t)(nb * 64) * STATE, 64, lds, STATE * 2, 0);
  __syncthreads();
  f32x4 acc[2][4];
  #pragma unroll
  for (int i = 0; i < 2; ++i)
    #pragma unroll
    for (int j = 0; j < 4; ++j) acc[i][j] = (f32x4){0.f, 0.f, 0.f, 0.f};
  kloop<STATE / 32, 2, 4, 4>(xsb + (size_t)grow0 * STATE, STATE, lds, STATE * 2, 0,
                             acc, lr, kbq);
  unsigned short frag[32];
  #pragma unroll
  for (int mi = 0; mi < 2; ++mi)
    #pragma unroll
    for (int ni = 0; ni < 4; ++ni)
      #pragma unroll
      for (int r = 0; r < 4; ++r) {
        const int row = grow0 + mi * 16 + kbq * 4 + r;
        const int col = nb * 64 + ni * 16 + lr;
        const float v = acc[mi][ni][r];
        frag[mi * 16 + ni * 4 + r] = f2bf(v);
        q0[(size_t)row * LDQ + col] = f2bf(fast_tanh(v));
      }
  unsigned short* xp = xcf + ((size_t)id * 512 + t) * 32;
  #pragma unroll
  for (int k = 0; k < 4; ++k)
    *(short8*)(xp + k * 8) = *(const short8*)(frag + k * 8);
}

// ---- one fixed-point step: qout = tanh(xc + qin @ D3_T panel) -------------
__global__ __launch_bounds__(512) void gemm_iter_kernel(
    const unsigned short* __restrict__ qin, const unsigned short* __restrict__ d3bt,
    const unsigned short* __restrict__ xcf, unsigned short* __restrict__ qout) {
  __shared__ alignas(16) char lds[131072];    // 64 rows x 2048 B
  TILE_IDX();
  stage_panel<NONLIN, 512>(d3bt + (size_t)(nb * 64) * NONLIN, 64, lds, NONLIN * 2, 0);
  __syncthreads();
  f32x4 acc[2][4];
  #pragma unroll
  for (int i = 0; i < 2; ++i)
    #pragma unroll
    for (int j = 0; j < 4; ++j) acc[i][j] = (f32x4){0.f, 0.f, 0.f, 0.f};
  kloop<NONLIN / 32, 2, 4, 4>(qin + (size_t)grow0 * LDQ, LDQ, lds,
                              NONLIN * 2, 0, acc, lr, kbq);
  short8 xcv[4];
  const unsigned short* xp = xcf + ((size_t)id * 512 + t) * 32;
  #pragma unroll
  for (int k = 0; k < 4; ++k) xcv[k] = *(const short8*)(xp + k * 8);
  #pragma unroll
  for (int mi = 0; mi < 2; ++mi)
    #pragma unroll
    for (int ni = 0; ni < 4; ++ni)
      #pragma unroll
      for (int r = 0; r < 4; ++r) {
        const int row = grow0 + mi * 16 + kbq * 4 + r;
        const int col = nb * 64 + ni * 16 + lr;
        const int fi = mi * 16 + ni * 4 + r;
        const float xv = bf2f((unsigned short)xcv[fi / 8][fi % 8]);
        qout[(size_t)row * LDQ + col] = f2bf(fast_tanh(xv + acc[mi][ni][r]));
      }
}

// ---- out = xs@A_T + q*@B1_T + us@B2_T  (f32, N=512; 256x32 tiles) ---------
__global__ __launch_bounds__(512) void gemm_out_kernel(
    const unsigned short* __restrict__ xsb, const unsigned short* __restrict__ abt,
    const unsigned short* __restrict__ q,   const unsigned short* __restrict__ b1bt,
    const unsigned short* __restrict__ usb, const unsigned short* __restrict__ b2bt,
    float* __restrict__ out) {
  __shared__ alignas(16) char lds[114688];    // 32 rows x 3584 B (A|B1|B2 concat)
  TILE_IDX();
  stage_panel<STATE,  512>(abt  + (size_t)(nb * 32) * STATE,  32, lds, 3584, 0);
  stage_panel<NONLIN, 512>(b1bt + (size_t)(nb * 32) * NONLIN, 32, lds, 3584, 1024);
  stage_panel<ACTION, 512>(b2bt + (size_t)(nb * 32) * ACTION, 32, lds, 3584, 3072);
  __syncthreads();
  f32x4 acc[2][2];
  #pragma unroll
  for (int i = 0; i < 2; ++i)
    #pragma unroll
    for (int j = 0; j < 2; ++j) acc[i][j] = (f32x4){0.f, 0.f, 0.f, 0.f};
  kloop<STATE / 32, 2, 2, 4>(xsb + (size_t)grow0 * STATE, STATE, lds, 3584, 0,
                             acc, lr, kbq);
  kloop<NONLIN / 32, 2, 2, 4>(q + (size_t)grow0 * LDQ, LDQ, lds, 3584, 1024,
                              acc, lr, kbq);
  kloop<ACTION / 32, 2, 2, 4>(usb + (size_t)grow0 * ACTION, ACTION, lds, 3584, 3072,
                              acc, lr, kbq);
  #pragma unroll
  for (int mi = 0; mi < 2; ++mi)
    #pragma unroll
    for (int ni = 0; ni < 2; ++ni)
      #pragma unroll
      for (int r = 0; r < 4; ++r) {
        const int row = grow0 + mi * 16 + kbq * 4 + r;
        const int col = nb * 32 + ni * 16 + lr;
        out[(size_t)row * STATE + col] = acc[mi][ni][r];
      }
}

extern "C" void kernel_launch(void* const* d_in, const int* in_sizes, int n_in,
                              void* d_out, int out_size, void* d_ws, size_t ws_size,
                              hipStream_t stream) {
  const float* xs   = (const float*)d_in[0];
  const float* us   = (const float*)d_in[1];
  const float* A_T  = (const float*)d_in[2];
  const float* B1_T = (const float*)d_in[3];
  const float* B2_T = (const float*)d_in[4];
  const float* C2_T = (const float*)d_in[5];
  const float* D3_T = (const float*)d_in[6];
  float* outp = (float*)d_out;

  size_t off = 0;
  auto take = [&](size_t b) {
    void* p = (char*)d_ws + off;
    off += (b + 255) & ~(size_t)255;
    return p;
  };
  unsigned short* xcf  = (unsigned short*)take((size_t)BATCH * NONLIN * 2);
  unsigned short* qa   = (unsigned short*)take((size_t)BATCH * LDQ * 2);
  unsigned short* qb   = (unsigned short*)take((size_t)BATCH * LDQ * 2);
  unsigned short* xsb  = (unsigned short*)take((size_t)BATCH * STATE * 2);
  unsigned short* usb  = (unsigned short*)take((size_t)BATCH * ACTION * 2);
  unsigned short* abt  = (unsigned short*)take((size_t)STATE * STATE * 2);
  unsigned short* b1bt = (unsigned short*)take((size_t)STATE * NONLIN * 2);
  unsigned short* b2bt = (unsigned short*)take((size_t)STATE * ACTION * 2);
  unsigned short* c2bt = (unsigned short*)take((size_t)NONLIN * STATE * 2);
  unsigned short* d3bt = (unsigned short*)take((size_t)NONLIN * NONLIN * 2);
  (void)ws_size; (void)in_sizes; (void)n_in; (void)out_size;

  // prologue: 2 launches
  convert_both_kernel<<<dim3(3072), dim3(256), 0, stream>>>(xs, us, xsb, usb);
  transpose_all_kernel<<<dim3(2432), dim3(32, 8), 0, stream>>>(
      A_T, B1_T, B2_T, C2_T, D3_T, abt, b1bt, b2bt, c2bt, d3bt);

  // fixed-point map 1: xc + q0
  gemm_xc_kernel<<<dim3(256), dim3(512), 0, stream>>>(xsb, c2bt, xcf, qa);

  // maps 2..NMAPS
  unsigned short* qin = qa;
  unsigned short* qout = qb;
  for (int it = 0; it < NMAPS - 1; ++it) {
    gemm_iter_kernel<<<dim3(256), dim3(512), 0, stream>>>(qin, d3bt, xcf, qout);
    unsigned short* tmp = qin; qin = qout; qout = tmp;
  }

  // out = xs@A_T + q*@B1_T + us@B2_T
  gemm_out_kernel<<<dim3(256), dim3(512), 0, stream>>>(
      xsb, abt, qin, b1bt, usb, b2bt, outp);
}